// Round 9
// baseline (6374.292 us; speedup 1.0000x reference)
//
#include <hip/hip_runtime.h>
#include <hip/hip_bf16.h>

#define LSEQ  1024
#define DEPTH 4

typedef __attribute__((ext_vector_type(8))) short short8;
typedef __attribute__((ext_vector_type(4))) float f32x4;

static __device__ __forceinline__ short f2bf(float f) {
    unsigned u = __builtin_bit_cast(unsigned, f);
    u += 0x7fffu + ((u >> 16) & 1u);
    return (short)(u >> 16);
}
static __device__ __forceinline__ float sigm(float x) { return __fdividef(1.f, 1.f + __expf(-x)); }
// tanh(g/2) = 2*sigmoid(g)-1
static __device__ __forceinline__ float tanh2(float g) { return 1.f - 2.f * __fdividef(1.f, 1.f + __expf(g)); }

static __device__ __forceinline__ void st32f(int* p, int v) { __hip_atomic_store(p, v, __ATOMIC_RELAXED, __HIP_MEMORY_SCOPE_AGENT); }
static __device__ __forceinline__ int  ld32f(const int* p) { return __hip_atomic_load(p, __ATOMIC_RELAXED, __HIP_MEMORY_SCOPE_AGENT); }
static __device__ __forceinline__ void st64g(unsigned long long* p, unsigned long long v) { __hip_atomic_store(p, v, __ATOMIC_RELAXED, __HIP_MEMORY_SCOPE_AGENT); }
static __device__ __forceinline__ unsigned long long ld64g(const unsigned long long* p) { return __hip_atomic_load(p, __ATOMIC_RELAXED, __HIP_MEMORY_SCOPE_AGENT); }

// h-exchange record: 8 B = [seq:16 | col0:bf16 | col1:bf16 | col2:bf16].
// 8B-aligned single st64g => single-copy atomic through MALL; the record is
// self-validating, so publish needs NO vmcnt drain and NO separate flag hop.
#define RECS_PER_ROW 22          // ceil(64 cols / 3)
#define SLICE_BYTES  (16 * RECS_PER_ROW * 8)   // 2816 B per (g,c) slice

extern "C" __global__ void __launch_bounds__(512)
__attribute__((amdgpu_waves_per_eu(2, 2)))
ctlstm_kernel(const float* __restrict__ x, const float* __restrict__ td,
              const float* __restrict__ Wi, const float* __restrict__ bi,
              const float* __restrict__ Wf, const float* __restrict__ bf,
              const float* __restrict__ Wie, const float* __restrict__ bie,
              const float* __restrict__ Wfe, const float* __restrict__ bfe,
              const float* __restrict__ Wz, const float* __restrict__ bz,
              const float* __restrict__ Wo, const float* __restrict__ bo,
              const float* __restrict__ Wd, const float* __restrict__ bdp,
              const float* __restrict__ betap,
              float* __restrict__ out,
              int* __restrict__ pflags, int* __restrict__ cflags,
              char* __restrict__ hbuf, float* __restrict__ ring)
{
    const int tid  = threadIdx.x;
    const int w    = tid >> 6;      // wave 0..7
    const int lane = tid & 63;
    const int l16  = lane & 15;
    const int lhi  = lane >> 4;

    if (blockIdx.x < 16) {
        // ===================== CONSUMER block (g, c) =====================
        const int g = blockIdx.x >> 2;
        const int c = blockIdx.x & 3;

        __shared__ float g_lds[24][17][18];                          // padded (R6)
        __shared__ __align__(16) unsigned short h_lds[2 * 16 * 256]; // 16 KB dbuf
        __shared__ float dvals[16];

        #pragma unroll
        for (int i = 0; i < 4; ++i) ((unsigned long long*)h_lds)[tid + i * 512] = 0ull;

        const float beta = betap[0];

        // ---- resident weight fragments (h-part, rows 256..511), R8 mapping ----
        short8 wfrag[4][8];
        #pragma unroll
        for (int i = 0; i < 4; ++i) {
            const bool hav = (i < 3) || (w == 7);
            if (hav) {
                if (i == 3) {
                    #pragma unroll
                    for (int kk = 0; kk < 8; ++kk) {
                        short8 f;
                        #pragma unroll
                        for (int e = 0; e < 8; ++e)
                            f[e] = (l16 == 0) ? f2bf(Wd[256 + kk * 32 + lhi * 8 + e]) : (short)0;
                        wfrag[i][kk] = f;
                    }
                } else {
                    const int T = w * 3 + i, gt = T >> 2, jt = T & 3;
                    const float* Wg;
                    switch (gt) {
                        case 0: Wg = Wi;  break;
                        case 1: Wg = Wf;  break;
                        case 2: Wg = Wie; break;
                        case 3: Wg = Wfe; break;
                        case 4: Wg = Wz;  break;
                        default: Wg = Wo; break;
                    }
                    const int col = c * 64 + jt * 16 + l16;
                    #pragma unroll
                    for (int kk = 0; kk < 8; ++kk) {
                        short8 f;
                        #pragma unroll
                        for (int e = 0; e < 8; ++e)
                            f[e] = f2bf(Wg[(256 + kk * 32 + lhi * 8 + e) * 256 + col]);
                        wfrag[i][kk] = f;
                    }
                }
            }
        }

        // update mapping: thread owns (row urow, cols c*64+2*up..+1)
        const int urow = tid >> 5;
        const int up   = tid & 31;
        float cC[2]  = {0.f, 0.f};
        float ceS[2] = {0.f, 0.f};
        float h2[2]  = {0.f, 0.f};

        // ---- fetch precompute (waves 1-3): 6 records per lane ----
        const int c2 = (c + w) & 3;       // peer for fetch waves
        int frow[6], frec[6], foff[6];
        bool fval[6];
        #pragma unroll
        for (int m = 0; m < 6; ++m) {
            const int idx = lane * 6 + m;
            fval[m] = (w >= 1 && w <= 3) && (idx < 16 * RECS_PER_ROW);
            const int row = idx / RECS_PER_ROW;
            const int r   = idx - row * RECS_PER_ROW;
            frow[m] = row; frec[m] = r;
            foff[m] = row * (RECS_PER_ROW * 8) + r * 8;
        }
        // publish precompute (waves 0,4,5,6,7): linear pool index
        const bool isPub = (w == 0) || (w >= 4);
        const int pubq = (w == 0) ? lane : (64 + (w - 4) * 64 + lane);  // 0..319

        f32x4 gx[4];
        auto load_gx = [&](int slot) {
            #pragma unroll
            for (int i = 0; i < 4; ++i) {
                const bool hav = (i < 3) || (w == 7);
                if (hav) {
                    const int T  = w * 3 + i;
                    const int ct = (i == 3) ? 96 : ((T >> 2) * 16 + c * 4 + (T & 3));
                    const unsigned long long* pp =
                        (const unsigned long long*)&ring[((size_t)(slot * 4 + g) * 97 + ct) * 256 + lane * 4];
                    union { unsigned long long q[2]; f32x4 v; } u;
                    u.q[0] = ld64g(pp); u.q[1] = ld64g(pp + 1);
                    gx[i] = u.v;
                }
            }
        };

        // prologue: producers must have finished steps 0 and 1
        {
            const int pidx = (lane & 3) * 4 + g;
            int v = (lane < 4) ? ld32f(&pflags[pidx * 32]) : 0x7fffffff;
            while (__any(v < 2)) {
                __builtin_amdgcn_s_sleep(8);
                v = (lane < 4) ? ld32f(&pflags[pidx * 32]) : 0x7fffffff;
            }
        }
        load_gx(0);
        __syncthreads();

        for (int t = 0; t < LSEQ; ++t) {
            const int zone_cur = (t & 1) * 8192;
            const int zone_nxt = ((t + 1) & 1) * 8192;
            // ---------------- phase G: recurrent GEMM + activations ----------------
            short8 hf[8];
            #pragma unroll
            for (int kk = 0; kk < 8; ++kk) {
                const int bo = zone_cur + l16 * 512 + ((kk * 64 + lhi * 16) ^ ((l16 & 7) << 4));
                hf[kk] = *(const short8*)((const char*)h_lds + bo);
            }
            f32x4 acc[4];
            #pragma unroll
            for (int i = 0; i < 4; ++i)
                if ((i < 3) || (w == 7)) acc[i] = gx[i];
            #pragma unroll
            for (int kk = 0; kk < 8; ++kk) {
                #pragma unroll
                for (int i = 0; i < 4; ++i)
                    if ((i < 3) || (w == 7))
                        acc[i] = __builtin_amdgcn_mfma_f32_16x16x32_bf16(hf[kk], wfrag[i][kk], acc[i], 0, 0, 0);
            }
            #pragma unroll
            for (int i = 0; i < 3; ++i) {
                const int T = w * 3 + i, gt = T >> 2;
                #pragma unroll
                for (int q = 0; q < 4; ++q) {
                    float v = acc[i][q];
                    v = (gt == 4) ? tanh2(v) : sigm(v);
                    g_lds[T][lhi * 4 + q][l16] = v;
                }
            }
            if (w == 7 && l16 == 0) {
                #pragma unroll
                for (int q = 0; q < 4; ++q) {
                    const float bg_ = beta * acc[3][q];
                    const float sp  = fmaxf(bg_, 0.f) + __logf(1.f + __expf(-fabsf(bg_)));
                    dvals[lhi * 4 + q] = __fdividef(sp, beta);
                }
            }
            __syncthreads();   // bar1: gates ready; gx(t) consumed by all waves

            // slot t consumed (barrier above orders this after gx use)
            if (tid == 0) st32f(&cflags[(g * 4 + c) * 32], t + 1);
            // early issue: next Gx tile (slot valid: pflags >= t+2 held on entry)
            if (t + 1 < LSEQ) load_gx((t + 1) & 3);
            // early issue: producer progress flags (checked at end of P)
            int pv = 0x7fffffff;
            if (t + 1 < LSEQ && lane < 4) pv = ld32f(&pflags[((lane & 3) * 4 + g) * 32]);

            // ---------------- phase U: state update (own 64-col slice) ----------------
            {
                // outputs[:, t, :] = h(t)  (fire-and-forget, never drained)
                *(float2*)(out + ((size_t)(g * 16 + urow) * LSEQ + t) * 256 + c * 64 + up * 2)
                    = make_float2(h2[0], h2[1]);

                const int jtl = up >> 3;
                const int cc2 = (up & 7) * 2;
                const float2 iv  = *(const float2*)&g_lds[0 * 4 + jtl][urow][cc2];
                const float2 fv  = *(const float2*)&g_lds[1 * 4 + jtl][urow][cc2];
                const float2 iev = *(const float2*)&g_lds[2 * 4 + jtl][urow][cc2];
                const float2 fev = *(const float2*)&g_lds[3 * 4 + jtl][urow][cc2];
                const float2 zv  = *(const float2*)&g_lds[4 * 4 + jtl][urow][cc2];
                const float2 ov  = *(const float2*)&g_lds[5 * 4 + jtl][urow][cc2];
                const float dn = dvals[urow];

                const float cs0 = fv.x * cC[0] + iv.x * zv.x;
                const float cs1 = fv.y * cC[1] + iv.y * zv.y;
                const float ce0 = fev.x * ceS[0] + iev.x * zv.x;
                const float ce1 = fev.y * ceS[1] + iev.y * zv.y;

                if (t + 1 < LSEQ) {
                    const float dtv = td[(size_t)(g * 16 + urow) * LSEQ + (t + 1)];
                    const float e   = __expf(-dn * dtv);
                    const float cn0 = cs0 + (ce0 - cs0) * e;
                    const float cn1 = cs1 + (ce1 - cs1) * e;
                    const float hv0 = ov.x * tanh2(2.f * cn0);
                    const float hv1 = ov.y * tanh2(2.f * cn1);
                    cC[0] = cn0; cC[1] = cn1;
                    ceS[0] = ce0; ceS[1] = ce1;
                    h2[0] = hv0; h2[1] = hv1;
                    const unsigned pk = (unsigned)(unsigned short)f2bf(hv0)
                                      | ((unsigned)(unsigned short)f2bf(hv1) << 16);
                    const int lin = c * 128 + up * 4;
                    *(unsigned*)((char*)h_lds + zone_nxt + urow * 512 + (lin ^ ((urow & 7) << 4))) = pk;
                } else {
                    float* so = out + (size_t)64 * LSEQ * 256 + (size_t)(g * 16 + urow) * 769;
                    const int jj = c * 64 + up * 2;
                    so[jj]           = ov.x; so[jj + 1]       = ov.y;
                    so[256 + jj]     = cs0;  so[256 + jj + 1] = cs1;
                    so[512 + jj]     = ce0;  so[512 + jj + 1] = ce1;
                    if (c == 0 && up == 0) so[768] = dn;
                }
            }
            __syncthreads();   // bar2: own h(t+1) slice complete in LDS (no vmcnt!)

            // ---------------- phase P: publish records, fetch peers, verify pflags ----------------
            if (t + 1 < LSEQ) {
                const int par = (t + 1) & 1;
                const unsigned long long seqlo = (unsigned long long)((t + 1) & 0xffff);

                if (isPub) {   // waves 0,4..7: publish own slice as self-validating records
                    char* sbase = hbuf + (size_t)(((par * 4 + g) * 4 + c)) * SLICE_BYTES;
                    for (int rec = pubq; rec < 16 * RECS_PER_ROW; rec += 320) {
                        const int row = rec / RECS_PER_ROW;
                        const int r   = rec - row * RECS_PER_ROW;
                        unsigned long long v = seqlo;
                        #pragma unroll
                        for (int j = 0; j < 3; ++j) {
                            const int col = r * 3 + j;
                            unsigned short hv = 0;
                            if (col < 64)
                                hv = *(const unsigned short*)((const char*)h_lds + zone_nxt
                                     + row * 512 + ((((c * 64 + col) * 2)) ^ ((row & 7) << 4)));
                            v |= ((unsigned long long)hv) << (16 * (j + 1));
                        }
                        st64g((unsigned long long*)(sbase + row * (RECS_PER_ROW * 8) + r * 8), v);
                    }
                } else {       // waves 1..3: fetch peer c2's slice by polling the data
                    char* sbase = hbuf + (size_t)(((par * 4 + g) * 4 + c2)) * SLICE_BYTES;
                    unsigned long long rv[6];
                    #pragma unroll
                    for (int m = 0; m < 6; ++m)
                        if (fval[m]) rv[m] = ld64g((const unsigned long long*)(sbase + foff[m]));
                    while (true) {
                        bool bad = false;
                        #pragma unroll
                        for (int m = 0; m < 6; ++m)
                            if (fval[m] && ((rv[m] & 0xffffull) != seqlo)) bad = true;
                        if (!__any(bad)) break;
                        #pragma unroll
                        for (int m = 0; m < 6; ++m)
                            if (fval[m] && ((rv[m] & 0xffffull) != seqlo))
                                rv[m] = ld64g((const unsigned long long*)(sbase + foff[m]));
                    }
                    #pragma unroll
                    for (int m = 0; m < 6; ++m) {
                        if (fval[m]) {
                            const int row = frow[m];
                            #pragma unroll
                            for (int j = 0; j < 3; ++j) {
                                const int col = frec[m] * 3 + j;
                                if (col < 64) {
                                    const unsigned short hv =
                                        (unsigned short)(rv[m] >> (16 * (j + 1)));
                                    *(unsigned short*)((char*)h_lds + zone_nxt + row * 512
                                        + ((((c2 * 64 + col) * 2)) ^ ((row & 7) << 4))) = hv;
                                }
                            }
                        }
                    }
                }
                // verify producer lead: entering t+1, pflags >= min(t+3, LSEQ)
                const int tgt = (t + 3 <= LSEQ) ? (t + 3) : LSEQ;
                while (__any(pv < tgt)) {
                    __builtin_amdgcn_s_sleep(2);
                    pv = (lane < 4) ? ld32f(&pflags[((lane & 3) * 4 + g) * 32]) : 0x7fffffff;
                }
            }
            __syncthreads();   // bar3: h(t+1) fully in LDS
        }
    } else {
        // ===================== PRODUCER block p (R8-verbatim) =====================
        const int p  = blockIdx.x - 16;   // 0..15
        const int g  = p & 3;
        const int qt = p >> 2;
        const int base_ct = qt * 24 + w * 3;
        const int nt = (qt == 3 && w == 7) ? 4 : 3;

        short8 wx[4][8];
        f32x4 bias[4];
        #pragma unroll
        for (int i = 0; i < 4; ++i) {
            if (i < nt) {
                const int ct = base_ct + i;
                if (ct == 96) {
                    const float bv = (l16 == 0) ? bdp[0] : 0.f;
                    bias[i] = f32x4{bv, bv, bv, bv};
                    #pragma unroll
                    for (int kk = 0; kk < 8; ++kk) {
                        short8 f;
                        #pragma unroll
                        for (int e = 0; e < 8; ++e)
                            f[e] = (l16 == 0) ? f2bf(Wd[kk * 32 + lhi * 8 + e]) : (short)0;
                        wx[i][kk] = f;
                    }
                } else {
                    const int gt = ct >> 4, jtg = ct & 15;
                    const float* Wg; const float* bg;
                    switch (gt) {
                        case 0: Wg = Wi;  bg = bi;  break;
                        case 1: Wg = Wf;  bg = bf;  break;
                        case 2: Wg = Wie; bg = bie; break;
                        case 3: Wg = Wfe; bg = bfe; break;
                        case 4: Wg = Wz;  bg = bz;  break;
                        default: Wg = Wo; bg = bo;  break;
                    }
                    const int col = jtg * 16 + l16;
                    const float bv = bg[col];
                    bias[i] = f32x4{bv, bv, bv, bv};
                    #pragma unroll
                    for (int kk = 0; kk < 8; ++kk) {
                        short8 f;
                        #pragma unroll
                        for (int e = 0; e < 8; ++e)
                            f[e] = f2bf(Wg[(kk * 32 + lhi * 8 + e) * 256 + col]);
                        wx[i][kk] = f;
                    }
                }
            }
        }

        const size_t xb = (size_t)(g * 16 + l16) * LSEQ;
        for (int t = 0; t < LSEQ; ++t) {
            if (t >= DEPTH) {   // back-pressure: consumers must have consumed slot
                const int cidx = g * 4 + (lane & 3);
                int v = (lane < 4) ? ld32f(&cflags[cidx * 32]) : 0x7fffffff;
                while (__any(v < t - (DEPTH - 1))) {
                    __builtin_amdgcn_s_sleep(8);
                    v = (lane < 4) ? ld32f(&cflags[cidx * 32]) : 0x7fffffff;
                }
            }
            const float* xp = x + (xb + t) * 256;
            short8 af[8];
            #pragma unroll
            for (int kk = 0; kk < 8; ++kk) {
                const f32x4 a  = *(const f32x4*)(xp + kk * 32 + lhi * 8);
                const f32x4 b2 = *(const f32x4*)(xp + kk * 32 + lhi * 8 + 4);
                short8 f;
                #pragma unroll
                for (int e = 0; e < 4; ++e) { f[e] = f2bf(a[e]); f[4 + e] = f2bf(b2[e]); }
                af[kk] = f;
            }
            f32x4 acc[4];
            #pragma unroll
            for (int i = 0; i < 4; ++i)
                if (i < nt) acc[i] = bias[i];
            #pragma unroll
            for (int kk = 0; kk < 8; ++kk) {
                #pragma unroll
                for (int i = 0; i < 4; ++i)
                    if (i < nt)
                        acc[i] = __builtin_amdgcn_mfma_f32_16x16x32_bf16(af[kk], wx[i][kk], acc[i], 0, 0, 0);
            }
            const int slot = t & (DEPTH - 1);
            #pragma unroll
            for (int i = 0; i < 4; ++i) {
                if (i < nt) {
                    const int ct = base_ct + i;
                    unsigned long long* pp =
                        (unsigned long long*)&ring[((size_t)(slot * 4 + g) * 97 + ct) * 256 + lane * 4];
                    union { unsigned long long q[2]; f32x4 v; } u;
                    u.v = acc[i];
                    st64g(pp, u.q[0]); st64g(pp + 1, u.q[1]);
                }
            }
            asm volatile("s_waitcnt vmcnt(0)" ::: "memory");
            __syncthreads();   // all waves' ring stores complete before flag
            if (tid == 0) st32f(&pflags[p * 32], t + 1);
        }
    }
}

extern "C" void kernel_launch(void* const* d_in, const int* in_sizes, int n_in,
                              void* d_out, int out_size, void* d_ws, size_t ws_size,
                              hipStream_t stream) {
    const float* x   = (const float*)d_in[0];
    const float* td  = (const float*)d_in[1];
    const float* Wi  = (const float*)d_in[2];
    const float* bi  = (const float*)d_in[3];
    const float* Wf  = (const float*)d_in[4];
    const float* bf  = (const float*)d_in[5];
    const float* Wie = (const float*)d_in[6];
    const float* bie = (const float*)d_in[7];
    const float* Wfe = (const float*)d_in[8];
    const float* bfe = (const float*)d_in[9];
    const float* Wz  = (const float*)d_in[10];
    const float* bz  = (const float*)d_in[11];
    const float* Wo  = (const float*)d_in[12];
    const float* bo  = (const float*)d_in[13];
    const float* Wd  = (const float*)d_in[14];
    const float* bd  = (const float*)d_in[15];
    const float* be  = (const float*)d_in[16];

    int* pflags = (int*)d_ws;                                // 16 * 128 B @ 0
    int* cflags = (int*)((char*)d_ws + 2048);                // 16 * 128 B
    char* hbuf  = (char*)d_ws + 4096;                        // 2*4*4*2816 = 90112 B
    float* ring = (float*)((char*)d_ws + 98304);             // 4*4*97*256 f32 = 1.59 MB

    // zero flags + hbuf seq words each launch (replay safety: stale seqs)
    hipMemsetAsync(d_ws, 0, 98304, stream);
    hipLaunchKernelGGL(ctlstm_kernel, dim3(32), dim3(512), 0, stream,
                       x, td, Wi, bi, Wf, bf, Wie, bie, Wfe, bfe, Wz, bz, Wo, bo,
                       Wd, bd, be, (float*)d_out, pflags, cflags, hbuf, ring);
}

// Round 10
// 5590.863 us; speedup vs baseline: 1.1401x; 1.1401x over previous
//
#include <hip/hip_runtime.h>
#include <hip/hip_bf16.h>

#define LSEQ  1024
#define DEPTH 4

typedef __attribute__((ext_vector_type(8))) short short8;
typedef __attribute__((ext_vector_type(4))) float f32x4;

static __device__ __forceinline__ short f2bf(float f) {
    unsigned u = __builtin_bit_cast(unsigned, f);
    u += 0x7fffu + ((u >> 16) & 1u);
    return (short)(u >> 16);
}
static __device__ __forceinline__ float sigm(float x) { return __fdividef(1.f, 1.f + __expf(-x)); }
// tanh(g/2) = 2*sigmoid(g)-1
static __device__ __forceinline__ float tanh2(float g) { return 1.f - 2.f * __fdividef(1.f, 1.f + __expf(g)); }

static __device__ __forceinline__ void st32f(int* p, int v) { __hip_atomic_store(p, v, __ATOMIC_RELAXED, __HIP_MEMORY_SCOPE_AGENT); }
static __device__ __forceinline__ int  ld32f(const int* p) { return __hip_atomic_load(p, __ATOMIC_RELAXED, __HIP_MEMORY_SCOPE_AGENT); }
static __device__ __forceinline__ void st64g(unsigned long long* p, unsigned long long v) { __hip_atomic_store(p, v, __ATOMIC_RELAXED, __HIP_MEMORY_SCOPE_AGENT); }
static __device__ __forceinline__ unsigned long long ld64g(const unsigned long long* p) { return __hip_atomic_load(p, __ATOMIC_RELAXED, __HIP_MEMORY_SCOPE_AGENT); }

// h-exchange record: 8 B = [seq:16 | h(col0):bf16 | h(col1):bf16 | 0].
// Published from REGISTERS in phase U the moment h is computed (fire-and-
// forget): no LDS round trip, no vmcnt drain, no flag. Poller polls data.
// Slice = 16 rows x 32 recs x 8 B = 4096 B per (parity,g,c).

extern "C" __global__ void __launch_bounds__(512)
__attribute__((amdgpu_waves_per_eu(2, 2)))
ctlstm_kernel(const float* __restrict__ x, const float* __restrict__ td,
              const float* __restrict__ Wi, const float* __restrict__ bi,
              const float* __restrict__ Wf, const float* __restrict__ bf,
              const float* __restrict__ Wie, const float* __restrict__ bie,
              const float* __restrict__ Wfe, const float* __restrict__ bfe,
              const float* __restrict__ Wz, const float* __restrict__ bz,
              const float* __restrict__ Wo, const float* __restrict__ bo,
              const float* __restrict__ Wd, const float* __restrict__ bdp,
              const float* __restrict__ betap,
              float* __restrict__ out,
              int* __restrict__ pflags, int* __restrict__ cflags,
              char* __restrict__ hbuf, float* __restrict__ ring)
{
    const int tid  = threadIdx.x;
    const int w    = tid >> 6;      // wave 0..7
    const int lane = tid & 63;
    const int l16  = lane & 15;
    const int lhi  = lane >> 4;

    if (blockIdx.x < 16) {
        // ===================== CONSUMER block (g, c) =====================
        const int g = blockIdx.x >> 2;
        const int c = blockIdx.x & 3;

        __shared__ float g_lds[24][17][18];                          // padded (R6)
        __shared__ __align__(16) unsigned short h_lds[2 * 16 * 256]; // 16 KB dbuf
        __shared__ float dvals[16];

        #pragma unroll
        for (int i = 0; i < 4; ++i) ((unsigned long long*)h_lds)[tid + i * 512] = 0ull;

        const float beta = betap[0];

        // ---- resident weight fragments (h-part, rows 256..511), R8 mapping ----
        short8 wfrag[4][8];
        #pragma unroll
        for (int i = 0; i < 4; ++i) {
            const bool hav = (i < 3) || (w == 7);
            if (hav) {
                if (i == 3) {
                    #pragma unroll
                    for (int kk = 0; kk < 8; ++kk) {
                        short8 f;
                        #pragma unroll
                        for (int e = 0; e < 8; ++e)
                            f[e] = (l16 == 0) ? f2bf(Wd[256 + kk * 32 + lhi * 8 + e]) : (short)0;
                        wfrag[i][kk] = f;
                    }
                } else {
                    const int T = w * 3 + i, gt = T >> 2, jt = T & 3;
                    const float* Wg;
                    switch (gt) {
                        case 0: Wg = Wi;  break;
                        case 1: Wg = Wf;  break;
                        case 2: Wg = Wie; break;
                        case 3: Wg = Wfe; break;
                        case 4: Wg = Wz;  break;
                        default: Wg = Wo; break;
                    }
                    const int col = c * 64 + jt * 16 + l16;
                    #pragma unroll
                    for (int kk = 0; kk < 8; ++kk) {
                        short8 f;
                        #pragma unroll
                        for (int e = 0; e < 8; ++e)
                            f[e] = f2bf(Wg[(256 + kk * 32 + lhi * 8 + e) * 256 + col]);
                        wfrag[i][kk] = f;
                    }
                }
            }
        }

        // update mapping: thread owns (row urow, cols c*64 + 2*up .. +1)
        const int urow = tid >> 5;
        const int up   = tid & 31;
        float cC[2]  = {0.f, 0.f};
        float ceS[2] = {0.f, 0.f};
        float h2[2]  = {0.f, 0.f};

        f32x4 gx[4];
        auto load_gx = [&](int slot) {
            #pragma unroll
            for (int i = 0; i < 4; ++i) {
                const bool hav = (i < 3) || (w == 7);
                if (hav) {
                    const int T  = w * 3 + i;
                    const int ct = (i == 3) ? 96 : ((T >> 2) * 16 + c * 4 + (T & 3));
                    const unsigned long long* pp =
                        (const unsigned long long*)&ring[((size_t)(slot * 4 + g) * 97 + ct) * 256 + lane * 4];
                    union { unsigned long long q[2]; f32x4 v; } u;
                    u.q[0] = ld64g(pp); u.q[1] = ld64g(pp + 1);
                    gx[i] = u.v;
                }
            }
        };

        // prologue: producers must have finished steps 0 and 1
        {
            const int pidx = (lane & 3) * 4 + g;
            int v = (lane < 4) ? ld32f(&pflags[pidx * 32]) : 0x7fffffff;
            while (__any(v < 2)) {
                __builtin_amdgcn_s_sleep(8);
                v = (lane < 4) ? ld32f(&pflags[pidx * 32]) : 0x7fffffff;
            }
        }
        load_gx(0);
        __syncthreads();

        for (int t = 0; t < LSEQ; ++t) {
            const int zone_cur = (t & 1) * 8192;
            const int zone_nxt = ((t + 1) & 1) * 8192;
            // ---------------- phase G: recurrent GEMM + activations ----------------
            short8 hf[8];
            #pragma unroll
            for (int kk = 0; kk < 8; ++kk) {
                const int bo = zone_cur + l16 * 512 + ((kk * 64 + lhi * 16) ^ ((l16 & 7) << 4));
                hf[kk] = *(const short8*)((const char*)h_lds + bo);
            }
            f32x4 acc[4];
            #pragma unroll
            for (int i = 0; i < 4; ++i)
                if ((i < 3) || (w == 7)) acc[i] = gx[i];
            #pragma unroll
            for (int kk = 0; kk < 8; ++kk) {
                #pragma unroll
                for (int i = 0; i < 4; ++i)
                    if ((i < 3) || (w == 7))
                        acc[i] = __builtin_amdgcn_mfma_f32_16x16x32_bf16(hf[kk], wfrag[i][kk], acc[i], 0, 0, 0);
            }
            #pragma unroll
            for (int i = 0; i < 3; ++i) {
                const int T = w * 3 + i, gt = T >> 2;
                #pragma unroll
                for (int q = 0; q < 4; ++q) {
                    float v = acc[i][q];
                    v = (gt == 4) ? tanh2(v) : sigm(v);
                    g_lds[T][lhi * 4 + q][l16] = v;
                }
            }
            if (w == 7 && l16 == 0) {
                #pragma unroll
                for (int q = 0; q < 4; ++q) {
                    const float bg_ = beta * acc[3][q];
                    const float sp  = fmaxf(bg_, 0.f) + __logf(1.f + __expf(-fabsf(bg_)));
                    dvals[lhi * 4 + q] = __fdividef(sp, beta);
                }
            }
            __syncthreads();   // bar1: gates ready; gx(t) consumed by all waves

            if (tid == 0) st32f(&cflags[(g * 4 + c) * 32], t + 1);
            if (t + 1 < LSEQ) load_gx((t + 1) & 3);   // slot valid: pflags >= t+2
            int pv = 0x7fffffff;
            if (t + 1 < LSEQ && lane < 4) pv = ld32f(&pflags[((lane & 3) * 4 + g) * 32]);

            // ---------------- phase U: update + REGISTER-direct record publish ----------------
            {
                // outputs[:, t, :] = h(t)  (fire-and-forget, never drained)
                *(float2*)(out + ((size_t)(g * 16 + urow) * LSEQ + t) * 256 + c * 64 + up * 2)
                    = make_float2(h2[0], h2[1]);

                const int jtl = up >> 3;
                const int cc2 = (up & 7) * 2;
                const float2 iv  = *(const float2*)&g_lds[0 * 4 + jtl][urow][cc2];
                const float2 fv  = *(const float2*)&g_lds[1 * 4 + jtl][urow][cc2];
                const float2 iev = *(const float2*)&g_lds[2 * 4 + jtl][urow][cc2];
                const float2 fev = *(const float2*)&g_lds[3 * 4 + jtl][urow][cc2];
                const float2 zv  = *(const float2*)&g_lds[4 * 4 + jtl][urow][cc2];
                const float2 ov  = *(const float2*)&g_lds[5 * 4 + jtl][urow][cc2];
                const float dn = dvals[urow];

                const float cs0 = fv.x * cC[0] + iv.x * zv.x;
                const float cs1 = fv.y * cC[1] + iv.y * zv.y;
                const float ce0 = fev.x * ceS[0] + iev.x * zv.x;
                const float ce1 = fev.y * ceS[1] + iev.y * zv.y;

                if (t + 1 < LSEQ) {
                    const float dtv = td[(size_t)(g * 16 + urow) * LSEQ + (t + 1)];
                    const float e   = __expf(-dn * dtv);
                    const float cn0 = cs0 + (ce0 - cs0) * e;
                    const float cn1 = cs1 + (ce1 - cs1) * e;
                    const float hv0 = ov.x * tanh2(2.f * cn0);
                    const float hv1 = ov.y * tanh2(2.f * cn1);
                    cC[0] = cn0; cC[1] = cn1;
                    ceS[0] = ce0; ceS[1] = ce1;
                    h2[0] = hv0; h2[1] = hv1;
                    const unsigned short b0 = (unsigned short)f2bf(hv0);
                    const unsigned short b1 = (unsigned short)f2bf(hv1);
                    // publish record NOW, straight from registers (no drain, no flag)
                    const unsigned long long rec =
                          (unsigned long long)((t + 1) & 0xffff)
                        | ((unsigned long long)b0 << 16)
                        | ((unsigned long long)b1 << 32);
                    char* sb = hbuf + ((size_t)((((t + 1) & 1) * 4 + g) * 4 + c)) * 4096;
                    st64g((unsigned long long*)(sb + (urow * 32 + up) * 8), rec);
                    // own slice into LDS (zone t+1)
                    const unsigned pk = (unsigned)b0 | ((unsigned)b1 << 16);
                    const int lin = c * 128 + up * 4;
                    *(unsigned*)((char*)h_lds + zone_nxt + urow * 512 + (lin ^ ((urow & 7) << 4))) = pk;
                } else {
                    float* so = out + (size_t)64 * LSEQ * 256 + (size_t)(g * 16 + urow) * 769;
                    const int jj = c * 64 + up * 2;
                    so[jj]           = ov.x; so[jj + 1]       = ov.y;
                    so[256 + jj]     = cs0;  so[256 + jj + 1] = cs1;
                    so[512 + jj]     = ce0;  so[512 + jj + 1] = ce1;
                    if (c == 0 && up == 0) so[768] = dn;
                }
            }

            // ---------------- phase P: fetch peer slices by polling records ----------------
            if (t + 1 < LSEQ) {
                if (w >= 1 && w <= 3) {
                    const int c2 = (c + w) & 3;
                    const unsigned long long seqlo = (unsigned long long)((t + 1) & 0xffff);
                    const char* sb = hbuf + ((size_t)((((t + 1) & 1) * 4 + g) * 4 + c2)) * 4096;
                    unsigned long long rv[8];
                    #pragma unroll
                    for (int m = 0; m < 8; ++m)
                        rv[m] = ld64g((const unsigned long long*)(sb + (lane * 8 + m) * 8));
                    while (true) {
                        bool bad = false;
                        #pragma unroll
                        for (int m = 0; m < 8; ++m)
                            if ((rv[m] & 0xffffull) != seqlo) bad = true;
                        if (!__any(bad)) break;
                        #pragma unroll
                        for (int m = 0; m < 8; ++m)
                            if ((rv[m] & 0xffffull) != seqlo)
                                rv[m] = ld64g((const unsigned long long*)(sb + (lane * 8 + m) * 8));
                    }
                    #pragma unroll
                    for (int m = 0; m < 8; ++m) {
                        const int idx = lane * 8 + m;
                        const int row = idx >> 5;
                        const int rec = idx & 31;
                        const unsigned val = (unsigned)(rv[m] >> 16);   // h0 | h1<<16
                        const int lin = c2 * 128 + rec * 4;
                        *(unsigned*)((char*)h_lds + zone_nxt + row * 512
                                     + (lin ^ ((row & 7) << 4))) = val;
                    }
                }
                // verify producer lead: entering t+1, pflags >= min(t+3, LSEQ)
                const int tgt = (t + 3 <= LSEQ) ? (t + 3) : LSEQ;
                while (__any(pv < tgt)) {
                    __builtin_amdgcn_s_sleep(2);
                    pv = (lane < 4) ? ld32f(&pflags[((lane & 3) * 4 + g) * 32]) : 0x7fffffff;
                }
            }
            __syncthreads();   // bar3: h(t+1) fully in LDS
        }
    } else {
        // ===================== PRODUCER block p (R8-verbatim) =====================
        const int p  = blockIdx.x - 16;   // 0..15
        const int g  = p & 3;
        const int qt = p >> 2;
        const int base_ct = qt * 24 + w * 3;
        const int nt = (qt == 3 && w == 7) ? 4 : 3;

        short8 wx[4][8];
        f32x4 bias[4];
        #pragma unroll
        for (int i = 0; i < 4; ++i) {
            if (i < nt) {
                const int ct = base_ct + i;
                if (ct == 96) {
                    const float bv = (l16 == 0) ? bdp[0] : 0.f;
                    bias[i] = f32x4{bv, bv, bv, bv};
                    #pragma unroll
                    for (int kk = 0; kk < 8; ++kk) {
                        short8 f;
                        #pragma unroll
                        for (int e = 0; e < 8; ++e)
                            f[e] = (l16 == 0) ? f2bf(Wd[kk * 32 + lhi * 8 + e]) : (short)0;
                        wx[i][kk] = f;
                    }
                } else {
                    const int gt = ct >> 4, jtg = ct & 15;
                    const float* Wg; const float* bg;
                    switch (gt) {
                        case 0: Wg = Wi;  bg = bi;  break;
                        case 1: Wg = Wf;  bg = bf;  break;
                        case 2: Wg = Wie; bg = bie; break;
                        case 3: Wg = Wfe; bg = bfe; break;
                        case 4: Wg = Wz;  bg = bz;  break;
                        default: Wg = Wo; bg = bo;  break;
                    }
                    const int col = jtg * 16 + l16;
                    const float bv = bg[col];
                    bias[i] = f32x4{bv, bv, bv, bv};
                    #pragma unroll
                    for (int kk = 0; kk < 8; ++kk) {
                        short8 f;
                        #pragma unroll
                        for (int e = 0; e < 8; ++e)
                            f[e] = f2bf(Wg[(kk * 32 + lhi * 8 + e) * 256 + col]);
                        wx[i][kk] = f;
                    }
                }
            }
        }

        const size_t xb = (size_t)(g * 16 + l16) * LSEQ;
        for (int t = 0; t < LSEQ; ++t) {
            if (t >= DEPTH) {   // back-pressure: consumers must have consumed slot
                const int cidx = g * 4 + (lane & 3);
                int v = (lane < 4) ? ld32f(&cflags[cidx * 32]) : 0x7fffffff;
                while (__any(v < t - (DEPTH - 1))) {
                    __builtin_amdgcn_s_sleep(8);
                    v = (lane < 4) ? ld32f(&cflags[cidx * 32]) : 0x7fffffff;
                }
            }
            const float* xp = x + (xb + t) * 256;
            short8 af[8];
            #pragma unroll
            for (int kk = 0; kk < 8; ++kk) {
                const f32x4 a  = *(const f32x4*)(xp + kk * 32 + lhi * 8);
                const f32x4 b2 = *(const f32x4*)(xp + kk * 32 + lhi * 8 + 4);
                short8 f;
                #pragma unroll
                for (int e = 0; e < 4; ++e) { f[e] = f2bf(a[e]); f[4 + e] = f2bf(b2[e]); }
                af[kk] = f;
            }
            f32x4 acc[4];
            #pragma unroll
            for (int i = 0; i < 4; ++i)
                if (i < nt) acc[i] = bias[i];
            #pragma unroll
            for (int kk = 0; kk < 8; ++kk) {
                #pragma unroll
                for (int i = 0; i < 4; ++i)
                    if (i < nt)
                        acc[i] = __builtin_amdgcn_mfma_f32_16x16x32_bf16(af[kk], wx[i][kk], acc[i], 0, 0, 0);
            }
            const int slot = t & (DEPTH - 1);
            #pragma unroll
            for (int i = 0; i < 4; ++i) {
                if (i < nt) {
                    const int ct = base_ct + i;
                    unsigned long long* pp =
                        (unsigned long long*)&ring[((size_t)(slot * 4 + g) * 97 + ct) * 256 + lane * 4];
                    union { unsigned long long q[2]; f32x4 v; } u;
                    u.v = acc[i];
                    st64g(pp, u.q[0]); st64g(pp + 1, u.q[1]);
                }
            }
            asm volatile("s_waitcnt vmcnt(0)" ::: "memory");
            __syncthreads();   // all waves' ring stores complete before flag
            if (tid == 0) st32f(&pflags[p * 32], t + 1);
        }
    }
}

extern "C" void kernel_launch(void* const* d_in, const int* in_sizes, int n_in,
                              void* d_out, int out_size, void* d_ws, size_t ws_size,
                              hipStream_t stream) {
    const float* x   = (const float*)d_in[0];
    const float* td  = (const float*)d_in[1];
    const float* Wi  = (const float*)d_in[2];
    const float* bi  = (const float*)d_in[3];
    const float* Wf  = (const float*)d_in[4];
    const float* bf  = (const float*)d_in[5];
    const float* Wie = (const float*)d_in[6];
    const float* bie = (const float*)d_in[7];
    const float* Wfe = (const float*)d_in[8];
    const float* bfe = (const float*)d_in[9];
    const float* Wz  = (const float*)d_in[10];
    const float* bz  = (const float*)d_in[11];
    const float* Wo  = (const float*)d_in[12];
    const float* bo  = (const float*)d_in[13];
    const float* Wd  = (const float*)d_in[14];
    const float* bd  = (const float*)d_in[15];
    const float* be  = (const float*)d_in[16];

    int* pflags = (int*)d_ws;                                // 16 * 128 B @ 0
    int* cflags = (int*)((char*)d_ws + 2048);                // 16 * 128 B
    char* hbuf  = (char*)d_ws + 4096;                        // 2*4*4*4096 = 131072 B
    float* ring = (float*)((char*)d_ws + 135168);            // 4*4*97*256 f32 = 1.59 MB

    // zero flags + hbuf (replay safety: stale seqs must not validate)
    hipMemsetAsync(d_ws, 0, 135168, stream);
    hipLaunchKernelGGL(ctlstm_kernel, dim3(32), dim3(512), 0, stream,
                       x, td, Wi, bi, Wf, bf, Wie, bie, Wfe, bfe, Wz, bz, Wo, bo,
                       Wd, bd, be, (float*)d_out, pflags, cflags, hbuf, ring);
}

// Round 11
// 5585.037 us; speedup vs baseline: 1.1413x; 1.0010x over previous
//
#include <hip/hip_runtime.h>
#include <hip/hip_bf16.h>

#define LSEQ  1024

typedef __attribute__((ext_vector_type(8))) short short8;
typedef __attribute__((ext_vector_type(4))) float f32x4;

static __device__ __forceinline__ short f2bf(float f) {
    unsigned u = __builtin_bit_cast(unsigned, f);
    u += 0x7fffu + ((u >> 16) & 1u);
    return (short)(u >> 16);
}
static __device__ __forceinline__ float sigm(float x) { return __fdividef(1.f, 1.f + __expf(-x)); }
// tanh(g/2) = 2*sigmoid(g)-1
static __device__ __forceinline__ float tanh2(float g) { return 1.f - 2.f * __fdividef(1.f, 1.f + __expf(g)); }

static __device__ __forceinline__ void st32f(int* p, int v) { __hip_atomic_store(p, v, __ATOMIC_RELAXED, __HIP_MEMORY_SCOPE_AGENT); }
static __device__ __forceinline__ int  ld32f(const int* p) { return __hip_atomic_load(p, __ATOMIC_RELAXED, __HIP_MEMORY_SCOPE_AGENT); }
static __device__ __forceinline__ void st64g(unsigned long long* p, unsigned long long v) { __hip_atomic_store(p, v, __ATOMIC_RELAXED, __HIP_MEMORY_SCOPE_AGENT); }
static __device__ __forceinline__ unsigned long long ld64g(const unsigned long long* p) { return __hip_atomic_load(p, __ATOMIC_RELAXED, __HIP_MEMORY_SCOPE_AGENT); }

// h-exchange record: 8 B = [seq:16 | h(col0):bf16 | h(col1):bf16 | 0], published
// from registers mid-U (R10). R11 single change: ring DEPTH 4 -> up to 16
// (runtime dmask/dlead) so producers run ~15 steps ahead and the
// producer<->consumer flag coupling leaves the per-step critical path.

extern "C" __global__ void __launch_bounds__(512)
__attribute__((amdgpu_waves_per_eu(2, 2)))
ctlstm_kernel(const float* __restrict__ x, const float* __restrict__ td,
              const float* __restrict__ Wi, const float* __restrict__ bi,
              const float* __restrict__ Wf, const float* __restrict__ bf,
              const float* __restrict__ Wie, const float* __restrict__ bie,
              const float* __restrict__ Wfe, const float* __restrict__ bfe,
              const float* __restrict__ Wz, const float* __restrict__ bz,
              const float* __restrict__ Wo, const float* __restrict__ bo,
              const float* __restrict__ Wd, const float* __restrict__ bdp,
              const float* __restrict__ betap,
              float* __restrict__ out,
              int* __restrict__ pflags, int* __restrict__ cflags,
              char* __restrict__ hbuf, float* __restrict__ ring,
              int dmask, int dlead)
{
    const int tid  = threadIdx.x;
    const int w    = tid >> 6;      // wave 0..7
    const int lane = tid & 63;
    const int l16  = lane & 15;
    const int lhi  = lane >> 4;

    if (blockIdx.x < 16) {
        // ===================== CONSUMER block (g, c) =====================
        const int g = blockIdx.x >> 2;
        const int c = blockIdx.x & 3;

        __shared__ float g_lds[24][17][18];                          // padded (R6)
        __shared__ __align__(16) unsigned short h_lds[2 * 16 * 256]; // 16 KB dbuf
        __shared__ float dvals[16];

        #pragma unroll
        for (int i = 0; i < 4; ++i) ((unsigned long long*)h_lds)[tid + i * 512] = 0ull;

        const float beta = betap[0];

        // ---- resident weight fragments (h-part, rows 256..511), R8 mapping ----
        short8 wfrag[4][8];
        #pragma unroll
        for (int i = 0; i < 4; ++i) {
            const bool hav = (i < 3) || (w == 7);
            if (hav) {
                if (i == 3) {
                    #pragma unroll
                    for (int kk = 0; kk < 8; ++kk) {
                        short8 f;
                        #pragma unroll
                        for (int e = 0; e < 8; ++e)
                            f[e] = (l16 == 0) ? f2bf(Wd[256 + kk * 32 + lhi * 8 + e]) : (short)0;
                        wfrag[i][kk] = f;
                    }
                } else {
                    const int T = w * 3 + i, gt = T >> 2, jt = T & 3;
                    const float* Wg;
                    switch (gt) {
                        case 0: Wg = Wi;  break;
                        case 1: Wg = Wf;  break;
                        case 2: Wg = Wie; break;
                        case 3: Wg = Wfe; break;
                        case 4: Wg = Wz;  break;
                        default: Wg = Wo; break;
                    }
                    const int col = c * 64 + jt * 16 + l16;
                    #pragma unroll
                    for (int kk = 0; kk < 8; ++kk) {
                        short8 f;
                        #pragma unroll
                        for (int e = 0; e < 8; ++e)
                            f[e] = f2bf(Wg[(256 + kk * 32 + lhi * 8 + e) * 256 + col]);
                        wfrag[i][kk] = f;
                    }
                }
            }
        }

        // update mapping: thread owns (row urow, cols c*64 + 2*up .. +1)
        const int urow = tid >> 5;
        const int up   = tid & 31;
        float cC[2]  = {0.f, 0.f};
        float ceS[2] = {0.f, 0.f};
        float h2[2]  = {0.f, 0.f};

        f32x4 gx[4];
        auto load_gx = [&](int slot) {
            #pragma unroll
            for (int i = 0; i < 4; ++i) {
                const bool hav = (i < 3) || (w == 7);
                if (hav) {
                    const int T  = w * 3 + i;
                    const int ct = (i == 3) ? 96 : ((T >> 2) * 16 + c * 4 + (T & 3));
                    const unsigned long long* pp =
                        (const unsigned long long*)&ring[((size_t)(slot * 4 + g) * 97 + ct) * 256 + lane * 4];
                    union { unsigned long long q[2]; f32x4 v; } u;
                    u.q[0] = ld64g(pp); u.q[1] = ld64g(pp + 1);
                    gx[i] = u.v;
                }
            }
        };

        // prologue: producers must have finished steps 0 and 1
        {
            const int pidx = (lane & 3) * 4 + g;
            int v = (lane < 4) ? ld32f(&pflags[pidx * 32]) : 0x7fffffff;
            while (__any(v < 2)) {
                __builtin_amdgcn_s_sleep(8);
                v = (lane < 4) ? ld32f(&pflags[pidx * 32]) : 0x7fffffff;
            }
        }
        load_gx(0);
        __syncthreads();

        for (int t = 0; t < LSEQ; ++t) {
            const int zone_cur = (t & 1) * 8192;
            const int zone_nxt = ((t + 1) & 1) * 8192;
            // ---------------- phase G: recurrent GEMM + activations ----------------
            short8 hf[8];
            #pragma unroll
            for (int kk = 0; kk < 8; ++kk) {
                const int bo = zone_cur + l16 * 512 + ((kk * 64 + lhi * 16) ^ ((l16 & 7) << 4));
                hf[kk] = *(const short8*)((const char*)h_lds + bo);
            }
            f32x4 acc[4];
            #pragma unroll
            for (int i = 0; i < 4; ++i)
                if ((i < 3) || (w == 7)) acc[i] = gx[i];
            #pragma unroll
            for (int kk = 0; kk < 8; ++kk) {
                #pragma unroll
                for (int i = 0; i < 4; ++i)
                    if ((i < 3) || (w == 7))
                        acc[i] = __builtin_amdgcn_mfma_f32_16x16x32_bf16(hf[kk], wfrag[i][kk], acc[i], 0, 0, 0);
            }
            #pragma unroll
            for (int i = 0; i < 3; ++i) {
                const int T = w * 3 + i, gt = T >> 2;
                #pragma unroll
                for (int q = 0; q < 4; ++q) {
                    float v = acc[i][q];
                    v = (gt == 4) ? tanh2(v) : sigm(v);
                    g_lds[T][lhi * 4 + q][l16] = v;
                }
            }
            if (w == 7 && l16 == 0) {
                #pragma unroll
                for (int q = 0; q < 4; ++q) {
                    const float bg_ = beta * acc[3][q];
                    const float sp  = fmaxf(bg_, 0.f) + __logf(1.f + __expf(-fabsf(bg_)));
                    dvals[lhi * 4 + q] = __fdividef(sp, beta);
                }
            }
            __syncthreads();   // bar1: gates ready; gx(t) consumed by all waves

            if (tid == 0) st32f(&cflags[(g * 4 + c) * 32], t + 1);
            if (t + 1 < LSEQ) load_gx((t + 1) & dmask);   // slot valid: pflags >= t+2
            int pv = 0x7fffffff;
            if (t + 1 < LSEQ && lane < 4) pv = ld32f(&pflags[((lane & 3) * 4 + g) * 32]);

            // ---------------- phase U: update + REGISTER-direct record publish ----------------
            {
                // outputs[:, t, :] = h(t)  (fire-and-forget, never drained)
                *(float2*)(out + ((size_t)(g * 16 + urow) * LSEQ + t) * 256 + c * 64 + up * 2)
                    = make_float2(h2[0], h2[1]);

                const int jtl = up >> 3;
                const int cc2 = (up & 7) * 2;
                const float2 iv  = *(const float2*)&g_lds[0 * 4 + jtl][urow][cc2];
                const float2 fv  = *(const float2*)&g_lds[1 * 4 + jtl][urow][cc2];
                const float2 iev = *(const float2*)&g_lds[2 * 4 + jtl][urow][cc2];
                const float2 fev = *(const float2*)&g_lds[3 * 4 + jtl][urow][cc2];
                const float2 zv  = *(const float2*)&g_lds[4 * 4 + jtl][urow][cc2];
                const float2 ov  = *(const float2*)&g_lds[5 * 4 + jtl][urow][cc2];
                const float dn = dvals[urow];

                const float cs0 = fv.x * cC[0] + iv.x * zv.x;
                const float cs1 = fv.y * cC[1] + iv.y * zv.y;
                const float ce0 = fev.x * ceS[0] + iev.x * zv.x;
                const float ce1 = fev.y * ceS[1] + iev.y * zv.y;

                if (t + 1 < LSEQ) {
                    const float dtv = td[(size_t)(g * 16 + urow) * LSEQ + (t + 1)];
                    const float e   = __expf(-dn * dtv);
                    const float cn0 = cs0 + (ce0 - cs0) * e;
                    const float cn1 = cs1 + (ce1 - cs1) * e;
                    const float hv0 = ov.x * tanh2(2.f * cn0);
                    const float hv1 = ov.y * tanh2(2.f * cn1);
                    cC[0] = cn0; cC[1] = cn1;
                    ceS[0] = ce0; ceS[1] = ce1;
                    h2[0] = hv0; h2[1] = hv1;
                    const unsigned short b0 = (unsigned short)f2bf(hv0);
                    const unsigned short b1 = (unsigned short)f2bf(hv1);
                    // publish record NOW, straight from registers (no drain, no flag)
                    const unsigned long long rec =
                          (unsigned long long)((t + 1) & 0xffff)
                        | ((unsigned long long)b0 << 16)
                        | ((unsigned long long)b1 << 32);
                    char* sb = hbuf + ((size_t)((((t + 1) & 1) * 4 + g) * 4 + c)) * 4096;
                    st64g((unsigned long long*)(sb + (urow * 32 + up) * 8), rec);
                    // own slice into LDS (zone t+1)
                    const unsigned pk = (unsigned)b0 | ((unsigned)b1 << 16);
                    const int lin = c * 128 + up * 4;
                    *(unsigned*)((char*)h_lds + zone_nxt + urow * 512 + (lin ^ ((urow & 7) << 4))) = pk;
                } else {
                    float* so = out + (size_t)64 * LSEQ * 256 + (size_t)(g * 16 + urow) * 769;
                    const int jj = c * 64 + up * 2;
                    so[jj]           = ov.x; so[jj + 1]       = ov.y;
                    so[256 + jj]     = cs0;  so[256 + jj + 1] = cs1;
                    so[512 + jj]     = ce0;  so[512 + jj + 1] = ce1;
                    if (c == 0 && up == 0) so[768] = dn;
                }
            }

            // ---------------- phase P: fetch peer slices by polling records ----------------
            if (t + 1 < LSEQ) {
                if (w >= 1 && w <= 3) {
                    const int c2 = (c + w) & 3;
                    const unsigned long long seqlo = (unsigned long long)((t + 1) & 0xffff);
                    const char* sb = hbuf + ((size_t)((((t + 1) & 1) * 4 + g) * 4 + c2)) * 4096;
                    unsigned long long rv[8];
                    #pragma unroll
                    for (int m = 0; m < 8; ++m)
                        rv[m] = ld64g((const unsigned long long*)(sb + (lane * 8 + m) * 8));
                    while (true) {
                        bool bad = false;
                        #pragma unroll
                        for (int m = 0; m < 8; ++m)
                            if ((rv[m] & 0xffffull) != seqlo) bad = true;
                        if (!__any(bad)) break;
                        #pragma unroll
                        for (int m = 0; m < 8; ++m)
                            if ((rv[m] & 0xffffull) != seqlo)
                                rv[m] = ld64g((const unsigned long long*)(sb + (lane * 8 + m) * 8));
                    }
                    #pragma unroll
                    for (int m = 0; m < 8; ++m) {
                        const int idx = lane * 8 + m;
                        const int row = idx >> 5;
                        const int rec = idx & 31;
                        const unsigned val = (unsigned)(rv[m] >> 16);   // h0 | h1<<16
                        const int lin = c2 * 128 + rec * 4;
                        *(unsigned*)((char*)h_lds + zone_nxt + row * 512
                                     + (lin ^ ((row & 7) << 4))) = val;
                    }
                }
                // verify producer lead: entering t+1, pflags >= min(t+3, LSEQ)
                // (with the deep ring producers are ~dlead ahead -> instant)
                const int tgt = (t + 3 <= LSEQ) ? (t + 3) : LSEQ;
                while (__any(pv < tgt)) {
                    __builtin_amdgcn_s_sleep(2);
                    pv = (lane < 4) ? ld32f(&pflags[((lane & 3) * 4 + g) * 32]) : 0x7fffffff;
                }
            }
            __syncthreads();   // bar3: h(t+1) fully in LDS
        }
    } else {
        // ===================== PRODUCER block p =====================
        const int p  = blockIdx.x - 16;   // 0..15
        const int g  = p & 3;
        const int qt = p >> 2;
        const int base_ct = qt * 24 + w * 3;
        const int nt = (qt == 3 && w == 7) ? 4 : 3;

        short8 wx[4][8];
        f32x4 bias[4];
        #pragma unroll
        for (int i = 0; i < 4; ++i) {
            if (i < nt) {
                const int ct = base_ct + i;
                if (ct == 96) {
                    const float bv = (l16 == 0) ? bdp[0] : 0.f;
                    bias[i] = f32x4{bv, bv, bv, bv};
                    #pragma unroll
                    for (int kk = 0; kk < 8; ++kk) {
                        short8 f;
                        #pragma unroll
                        for (int e = 0; e < 8; ++e)
                            f[e] = (l16 == 0) ? f2bf(Wd[kk * 32 + lhi * 8 + e]) : (short)0;
                        wx[i][kk] = f;
                    }
                } else {
                    const int gt = ct >> 4, jtg = ct & 15;
                    const float* Wg; const float* bg;
                    switch (gt) {
                        case 0: Wg = Wi;  bg = bi;  break;
                        case 1: Wg = Wf;  bg = bf;  break;
                        case 2: Wg = Wie; bg = bie; break;
                        case 3: Wg = Wfe; bg = bfe; break;
                        case 4: Wg = Wz;  bg = bz;  break;
                        default: Wg = Wo; bg = bo;  break;
                    }
                    const int col = jtg * 16 + l16;
                    const float bv = bg[col];
                    bias[i] = f32x4{bv, bv, bv, bv};
                    #pragma unroll
                    for (int kk = 0; kk < 8; ++kk) {
                        short8 f;
                        #pragma unroll
                        for (int e = 0; e < 8; ++e)
                            f[e] = f2bf(Wg[(kk * 32 + lhi * 8 + e) * 256 + col]);
                        wx[i][kk] = f;
                    }
                }
            }
        }

        const size_t xb = (size_t)(g * 16 + l16) * LSEQ;
        for (int t = 0; t < LSEQ; ++t) {
            if (t > dlead) {   // back-pressure: slot's previous content consumed
                const int cidx = g * 4 + (lane & 3);
                int v = (lane < 4) ? ld32f(&cflags[cidx * 32]) : 0x7fffffff;
                while (__any(v < t - dlead)) {
                    __builtin_amdgcn_s_sleep(8);
                    v = (lane < 4) ? ld32f(&cflags[cidx * 32]) : 0x7fffffff;
                }
            }
            const float* xp = x + (xb + t) * 256;
            short8 af[8];
            #pragma unroll
            for (int kk = 0; kk < 8; ++kk) {
                const f32x4 a  = *(const f32x4*)(xp + kk * 32 + lhi * 8);
                const f32x4 b2 = *(const f32x4*)(xp + kk * 32 + lhi * 8 + 4);
                short8 f;
                #pragma unroll
                for (int e = 0; e < 4; ++e) { f[e] = f2bf(a[e]); f[4 + e] = f2bf(b2[e]); }
                af[kk] = f;
            }
            f32x4 acc[4];
            #pragma unroll
            for (int i = 0; i < 4; ++i)
                if (i < nt) acc[i] = bias[i];
            #pragma unroll
            for (int kk = 0; kk < 8; ++kk) {
                #pragma unroll
                for (int i = 0; i < 4; ++i)
                    if (i < nt)
                        acc[i] = __builtin_amdgcn_mfma_f32_16x16x32_bf16(af[kk], wx[i][kk], acc[i], 0, 0, 0);
            }
            const int slot = t & dmask;
            #pragma unroll
            for (int i = 0; i < 4; ++i) {
                if (i < nt) {
                    const int ct = base_ct + i;
                    unsigned long long* pp =
                        (unsigned long long*)&ring[((size_t)(slot * 4 + g) * 97 + ct) * 256 + lane * 4];
                    union { unsigned long long q[2]; f32x4 v; } u;
                    u.v = acc[i];
                    st64g(pp, u.q[0]); st64g(pp + 1, u.q[1]);
                }
            }
            asm volatile("s_waitcnt vmcnt(0)" ::: "memory");
            __syncthreads();   // all waves' ring stores complete before flag
            if (tid == 0) st32f(&pflags[p * 32], t + 1);
        }
    }
}

extern "C" void kernel_launch(void* const* d_in, const int* in_sizes, int n_in,
                              void* d_out, int out_size, void* d_ws, size_t ws_size,
                              hipStream_t stream) {
    const float* x   = (const float*)d_in[0];
    const float* td  = (const float*)d_in[1];
    const float* Wi  = (const float*)d_in[2];
    const float* bi  = (const float*)d_in[3];
    const float* Wf  = (const float*)d_in[4];
    const float* bf  = (const float*)d_in[5];
    const float* Wie = (const float*)d_in[6];
    const float* bie = (const float*)d_in[7];
    const float* Wfe = (const float*)d_in[8];
    const float* bfe = (const float*)d_in[9];
    const float* Wz  = (const float*)d_in[10];
    const float* bz  = (const float*)d_in[11];
    const float* Wo  = (const float*)d_in[12];
    const float* bo  = (const float*)d_in[13];
    const float* Wd  = (const float*)d_in[14];
    const float* bd  = (const float*)d_in[15];
    const float* be  = (const float*)d_in[16];

    int* pflags = (int*)d_ws;                                // 16 * 128 B @ 0
    int* cflags = (int*)((char*)d_ws + 2048);                // 16 * 128 B
    char* hbuf  = (char*)d_ws + 4096;                        // 2*4*4*4096 = 131072 B
    float* ring = (float*)((char*)d_ws + 135168);

    // choose ring depth by available workspace (per-slot = 4*97*256*4 B)
    const size_t slot_bytes = (size_t)4 * 97 * 256 * 4;
    int depth = 4;
    if (ws_size >= 135168 + 16 * slot_bytes) depth = 16;
    else if (ws_size >= 135168 + 8 * slot_bytes) depth = 8;

    // zero flags + hbuf (replay safety: stale seqs must not validate)
    hipMemsetAsync(d_ws, 0, 135168, stream);
    hipLaunchKernelGGL(ctlstm_kernel, dim3(32), dim3(512), 0, stream,
                       x, td, Wi, bi, Wf, bf, Wie, bie, Wfe, bfe, Wz, bz, Wo, bo,
                       Wd, bd, be, (float*)d_out, pflags, cflags, hbuf, ring,
                       depth - 1, depth - 1);
}

// Round 13
// 5333.173 us; speedup vs baseline: 1.1952x; 1.0472x over previous
//
#include <hip/hip_runtime.h>
#include <hip/hip_bf16.h>

#define LSEQ 1024

typedef __attribute__((ext_vector_type(8))) short short8;
typedef __attribute__((ext_vector_type(4))) float f32x4;
typedef __attribute__((ext_vector_type(4))) unsigned short us4;

static __device__ __forceinline__ short f2bf(float f) {
    unsigned u = __builtin_bit_cast(unsigned, f);
    u += 0x7fffu + ((u >> 16) & 1u);
    return (short)(u >> 16);
}
static __device__ __forceinline__ float bf2f(unsigned short s) {
    unsigned u = ((unsigned)s) << 16;
    return __builtin_bit_cast(float, u);
}
static __device__ __forceinline__ float sigm(float x) { return __fdividef(1.f, 1.f + __expf(-x)); }
static __device__ __forceinline__ float tanh2(float g) { return 1.f - 2.f * __fdividef(1.f, 1.f + __expf(g)); }

static __device__ __forceinline__ void st64g(unsigned long long* p, unsigned long long v) { __hip_atomic_store(p, v, __ATOMIC_RELAXED, __HIP_MEMORY_SCOPE_AGENT); }
static __device__ __forceinline__ unsigned long long ld64g(const unsigned long long* p) { return __hip_atomic_load(p, __ATOMIC_RELAXED, __HIP_MEMORY_SCOPE_AGENT); }

// ============ PHASE 1: Gx[t] = x_t @ Wx + b  (no recurrence, no flags) ============
// Visibility to phase 2 via kernel-launch boundary (guaranteed), NOT atomics.
extern "C" __global__ void __launch_bounds__(512)
gx_kernel(const float* __restrict__ x,
          const float* __restrict__ Wi, const float* __restrict__ bi,
          const float* __restrict__ Wf, const float* __restrict__ bf,
          const float* __restrict__ Wie, const float* __restrict__ bie,
          const float* __restrict__ Wfe, const float* __restrict__ bfe,
          const float* __restrict__ Wz, const float* __restrict__ bz,
          const float* __restrict__ Wo, const float* __restrict__ bo,
          const float* __restrict__ Wd, const float* __restrict__ bdp,
          unsigned short* __restrict__ ringbf, int t0, int spb)
{
    const int tid  = threadIdx.x;
    const int w    = tid >> 6;
    const int lane = tid & 63;
    const int l16  = lane & 15;
    const int lhi  = lane >> 4;

    const int p  = blockIdx.x & 15;
    const int sl = blockIdx.x >> 4;      // t-slice 0..7
    const int g  = p & 3;
    const int qt = p >> 2;
    const int base_ct = qt * 24 + w * 3;
    const int nt = (qt == 3 && w == 7) ? 4 : 3;

    short8 wx[4][8];
    f32x4 bias[4];
    #pragma unroll
    for (int i = 0; i < 4; ++i) {
        if (i < nt) {
            const int ct = base_ct + i;
            if (ct == 96) {
                const float bv = (l16 == 0) ? bdp[0] : 0.f;
                bias[i] = f32x4{bv, bv, bv, bv};
                #pragma unroll
                for (int kk = 0; kk < 8; ++kk) {
                    short8 f;
                    #pragma unroll
                    for (int e = 0; e < 8; ++e)
                        f[e] = (l16 == 0) ? f2bf(Wd[kk * 32 + lhi * 8 + e]) : (short)0;
                    wx[i][kk] = f;
                }
            } else {
                const int gt = ct >> 4, jtg = ct & 15;
                const float* Wg; const float* bg;
                switch (gt) {
                    case 0: Wg = Wi;  bg = bi;  break;
                    case 1: Wg = Wf;  bg = bf;  break;
                    case 2: Wg = Wie; bg = bie; break;
                    case 3: Wg = Wfe; bg = bfe; break;
                    case 4: Wg = Wz;  bg = bz;  break;
                    default: Wg = Wo; bg = bo;  break;
                }
                const int col = jtg * 16 + l16;
                const float bv = bg[col];
                bias[i] = f32x4{bv, bv, bv, bv};
                #pragma unroll
                for (int kk = 0; kk < 8; ++kk) {
                    short8 f;
                    #pragma unroll
                    for (int e = 0; e < 8; ++e)
                        f[e] = f2bf(Wg[(kk * 32 + lhi * 8 + e) * 256 + col]);
                    wx[i][kk] = f;
                }
            }
        }
    }

    const size_t xb = (size_t)(g * 16 + l16) * LSEQ;
    const int tb = t0 + sl * spb;
    for (int ti = 0; ti < spb; ++ti) {
        const int t = tb + ti;
        const float* xp = x + (xb + t) * 256;
        short8 af[8];
        #pragma unroll
        for (int kk = 0; kk < 8; ++kk) {
            const f32x4 a  = *(const f32x4*)(xp + kk * 32 + lhi * 8);
            const f32x4 b2 = *(const f32x4*)(xp + kk * 32 + lhi * 8 + 4);
            short8 f;
            #pragma unroll
            for (int e = 0; e < 4; ++e) { f[e] = f2bf(a[e]); f[4 + e] = f2bf(b2[e]); }
            af[kk] = f;
        }
        f32x4 acc[4];
        #pragma unroll
        for (int i = 0; i < 4; ++i)
            if (i < nt) acc[i] = bias[i];
        #pragma unroll
        for (int kk = 0; kk < 8; ++kk) {
            #pragma unroll
            for (int i = 0; i < 4; ++i)
                if (i < nt)
                    acc[i] = __builtin_amdgcn_mfma_f32_16x16x32_bf16(af[kk], wx[i][kk], acc[i], 0, 0, 0);
        }
        #pragma unroll
        for (int i = 0; i < 4; ++i) {
            if (i < nt) {
                us4 o;
                #pragma unroll
                for (int e = 0; e < 4; ++e) o[e] = (unsigned short)f2bf(acc[i][e]);
                us4* pp = (us4*)&ringbf[(((size_t)(t - t0) * 4 + g) * 97 + base_ct + i) * 256 + lane * 4];
                __builtin_nontemporal_store(o, pp);
            }
        }
    }
}

// ============ PHASE 2: recurrence over [t0, t1). Gx via plain loads. ============
// h-exchange: R10-verbatim self-validating 8B records (agent atomics).
extern "C" __global__ void __launch_bounds__(512)
__attribute__((amdgpu_waves_per_eu(2, 2)))
rec_kernel(const float* __restrict__ td,
           const float* __restrict__ Wi, const float* __restrict__ Wf,
           const float* __restrict__ Wie, const float* __restrict__ Wfe,
           const float* __restrict__ Wz, const float* __restrict__ Wo,
           const float* __restrict__ Wd, const float* __restrict__ betap,
           float* __restrict__ out, char* __restrict__ hbuf,
           const unsigned short* __restrict__ ringbf, char* __restrict__ stbuf,
           int t0, int t1)
{
    const int tid  = threadIdx.x;
    const int w    = tid >> 6;
    const int lane = tid & 63;
    const int l16  = lane & 15;
    const int lhi  = lane >> 4;

    const int g = blockIdx.x >> 2;
    const int c = blockIdx.x & 3;

    __shared__ float g_lds[24][17][18];
    __shared__ __align__(16) unsigned short h_lds[2 * 16 * 256];
    __shared__ float dvals[16];
    __shared__ float wd_lds[256];

    if (tid < 256) wd_lds[tid] = Wd[256 + tid];

    char* myst = stbuf + (size_t)blockIdx.x * 32768;
    if (t0 == 0) {
        #pragma unroll
        for (int i = 0; i < 4; ++i) ((unsigned long long*)h_lds)[tid + i * 512] = 0ull;
    } else {
        unsigned long long* dz = (unsigned long long*)((char*)h_lds + (t0 & 1) * 8192);
        const unsigned long long* sz = (const unsigned long long*)myst;
        dz[tid] = sz[tid];
        dz[tid + 512] = sz[tid + 512];
    }

    const float beta = betap[0];

    // resident gate weights (h-part rows 256..511): 3 tiles/wave, 96 VGPR
    short8 wfrag[3][8];
    #pragma unroll
    for (int i = 0; i < 3; ++i) {
        const int T = w * 3 + i, gt = T >> 2, jt = T & 3;
        const float* Wg;
        switch (gt) {
            case 0: Wg = Wi;  break;
            case 1: Wg = Wf;  break;
            case 2: Wg = Wie; break;
            case 3: Wg = Wfe; break;
            case 4: Wg = Wz;  break;
            default: Wg = Wo; break;
        }
        const int col = c * 64 + jt * 16 + l16;
        #pragma unroll
        for (int kk = 0; kk < 8; ++kk) {
            short8 f;
            #pragma unroll
            for (int e = 0; e < 8; ++e)
                f[e] = f2bf(Wg[(256 + kk * 32 + lhi * 8 + e) * 256 + col]);
            wfrag[i][kk] = f;
        }
    }

    const int urow = tid >> 5;
    const int up   = tid & 31;
    float cC[2], ceS[2], h2[2];
    if (t0 == 0) {
        cC[0] = cC[1] = ceS[0] = ceS[1] = h2[0] = h2[1] = 0.f;
    } else {
        const float* fs = (const float*)(myst + 8192) + tid * 6;
        cC[0] = fs[0]; cC[1] = fs[1]; ceS[0] = fs[2]; ceS[1] = fs[3];
        h2[0] = fs[4]; h2[1] = fs[5];
    }

    int myct[3];
    #pragma unroll
    for (int i = 0; i < 3; ++i) {
        const int T = w * 3 + i;
        myct[i] = (T >> 2) * 16 + c * 4 + (T & 3);
    }

    us4 gxr[3];
    unsigned short gxd = 0;
    auto load_gx = [&](int tl) {
        #pragma unroll
        for (int i = 0; i < 3; ++i)
            gxr[i] = *(const us4*)&ringbf[(((size_t)tl * 4 + g) * 97 + myct[i]) * 256 + lane * 4];
        if (w == 0)
            gxd = ringbf[(((size_t)tl * 4 + g) * 97 + 96) * 256 + (l16 >> 2) * 64 + (l16 & 3)];
    };
    load_gx(0);
    __syncthreads();

    for (int t = t0; t < t1; ++t) {
        const int zone_cur = (t & 1) * 8192;
        const int zone_nxt = ((t + 1) & 1) * 8192;

        // ---------- phase G ----------
        short8 hf[8];
        #pragma unroll
        for (int kk = 0; kk < 8; ++kk) {
            const int bo = zone_cur + l16 * 512 + ((kk * 64 + lhi * 16) ^ ((l16 & 7) << 4));
            hf[kk] = *(const short8*)((const char*)h_lds + bo);
        }
        f32x4 acc[3];
        #pragma unroll
        for (int i = 0; i < 3; ++i)
            acc[i] = f32x4{bf2f(gxr[i][0]), bf2f(gxr[i][1]), bf2f(gxr[i][2]), bf2f(gxr[i][3])};
        #pragma unroll
        for (int kk = 0; kk < 8; ++kk) {
            #pragma unroll
            for (int i = 0; i < 3; ++i)
                acc[i] = __builtin_amdgcn_mfma_f32_16x16x32_bf16(hf[kk], wfrag[i][kk], acc[i], 0, 0, 0);
        }
        #pragma unroll
        for (int i = 0; i < 3; ++i) {
            const int T = w * 3 + i, gt = T >> 2;
            #pragma unroll
            for (int q = 0; q < 4; ++q) {
                float v = acc[i][q];
                v = (gt == 4) ? tanh2(v) : sigm(v);
                g_lds[T][lhi * 4 + q][l16] = v;
            }
        }
        if (w == 0) {   // delta head via VALU: row=l16, k-slice=lhi
            float part = 0.f;
            #pragma unroll
            for (int kb = 0; kb < 8; ++kb) {
                const int bo = zone_cur + l16 * 512 + (((lhi * 64 + kb * 8) * 2) ^ ((l16 & 7) << 4));
                const short8 hv = *(const short8*)((const char*)h_lds + bo);
                #pragma unroll
                for (int e = 0; e < 8; ++e)
                    part += bf2f((unsigned short)hv[e]) * wd_lds[lhi * 64 + kb * 8 + e];
            }
            part += __shfl_xor(part, 16);
            part += __shfl_xor(part, 32);
            const float gd = part + bf2f(gxd);
            const float bg_ = beta * gd;
            const float sp  = fmaxf(bg_, 0.f) + __logf(1.f + __expf(-fabsf(bg_)));
            if (lane < 16) dvals[l16] = __fdividef(sp, beta);
        }
        __syncthreads();   // bar1: gates+dvals ready; gxr consumed

        if (t + 1 < t1) load_gx(t + 1 - t0);   // plain loads, no flags

        // ---------- phase U ----------
        {
            *(float2*)(out + ((size_t)(g * 16 + urow) * LSEQ + t) * 256 + c * 64 + up * 2)
                = make_float2(h2[0], h2[1]);

            const int jtl = up >> 3;
            const int cc2 = (up & 7) * 2;
            const float2 iv  = *(const float2*)&g_lds[0 * 4 + jtl][urow][cc2];
            const float2 fv  = *(const float2*)&g_lds[1 * 4 + jtl][urow][cc2];
            const float2 iev = *(const float2*)&g_lds[2 * 4 + jtl][urow][cc2];
            const float2 fev = *(const float2*)&g_lds[3 * 4 + jtl][urow][cc2];
            const float2 zv  = *(const float2*)&g_lds[4 * 4 + jtl][urow][cc2];
            const float2 ov  = *(const float2*)&g_lds[5 * 4 + jtl][urow][cc2];
            const float dn = dvals[urow];

            const float cs0 = fv.x * cC[0] + iv.x * zv.x;
            const float cs1 = fv.y * cC[1] + iv.y * zv.y;
            const float ce0 = fev.x * ceS[0] + iev.x * zv.x;
            const float ce1 = fev.y * ceS[1] + iev.y * zv.y;

            if (t + 1 < LSEQ) {
                const float dtv = td[(size_t)(g * 16 + urow) * LSEQ + (t + 1)];
                const float e   = __expf(-dn * dtv);
                const float cn0 = cs0 + (ce0 - cs0) * e;
                const float cn1 = cs1 + (ce1 - cs1) * e;
                const float hv0 = ov.x * tanh2(2.f * cn0);
                const float hv1 = ov.y * tanh2(2.f * cn1);
                cC[0] = cn0; cC[1] = cn1;
                ceS[0] = ce0; ceS[1] = ce1;
                h2[0] = hv0; h2[1] = hv1;
                const unsigned short b0 = (unsigned short)f2bf(hv0);
                const unsigned short b1 = (unsigned short)f2bf(hv1);
                const unsigned long long rec =
                      (unsigned long long)((t + 1) & 0xffff)
                    | ((unsigned long long)b0 << 16)
                    | ((unsigned long long)b1 << 32);
                char* sb = hbuf + ((size_t)((((t + 1) & 1) * 4 + g) * 4 + c)) * 4096;
                st64g((unsigned long long*)(sb + (urow * 32 + up) * 8), rec);
                const unsigned pk = (unsigned)b0 | ((unsigned)b1 << 16);
                const int lin = c * 128 + up * 4;
                *(unsigned*)((char*)h_lds + zone_nxt + urow * 512 + (lin ^ ((urow & 7) << 4))) = pk;
            } else {
                float* so = out + (size_t)64 * LSEQ * 256 + (size_t)(g * 16 + urow) * 769;
                const int jj = c * 64 + up * 2;
                so[jj]           = ov.x; so[jj + 1]       = ov.y;
                so[256 + jj]     = cs0;  so[256 + jj + 1] = cs1;
                so[512 + jj]     = ce0;  so[512 + jj + 1] = ce1;
                if (c == 0 && up == 0) so[768] = dn;
            }
        }

        // ---------- phase P: fetch peer slices by polling records ----------
        if (t + 1 < LSEQ) {
            if (w >= 1 && w <= 3) {
                const int c2 = (c + w) & 3;
                const unsigned long long seqlo = (unsigned long long)((t + 1) & 0xffff);
                const char* sb = hbuf + ((size_t)((((t + 1) & 1) * 4 + g) * 4 + c2)) * 4096;
                unsigned long long rv[8];
                #pragma unroll
                for (int m = 0; m < 8; ++m)
                    rv[m] = ld64g((const unsigned long long*)(sb + (lane * 8 + m) * 8));
                while (true) {
                    bool bad = false;
                    #pragma unroll
                    for (int m = 0; m < 8; ++m)
                        if ((rv[m] & 0xffffull) != seqlo) bad = true;
                    if (!__any(bad)) break;
                    #pragma unroll
                    for (int m = 0; m < 8; ++m)
                        if ((rv[m] & 0xffffull) != seqlo)
                            rv[m] = ld64g((const unsigned long long*)(sb + (lane * 8 + m) * 8));
                }
                #pragma unroll
                for (int m = 0; m < 8; ++m) {
                    const int idx = lane * 8 + m;
                    const int row = idx >> 5;
                    const int rcc = idx & 31;
                    const unsigned val = (unsigned)(rv[m] >> 16);
                    const int lin = c2 * 128 + rcc * 4;
                    *(unsigned*)((char*)h_lds + zone_nxt + row * 512
                                 + (lin ^ ((row & 7) << 4))) = val;
                }
            }
        }
        __syncthreads();   // bar3: h(t+1) fully in LDS
    }

    // chunk-boundary state save
    if (t1 < LSEQ) {
        unsigned long long* dz = (unsigned long long*)myst;
        const unsigned long long* sz = (const unsigned long long*)((char*)h_lds + (t1 & 1) * 8192);
        dz[tid] = sz[tid];
        dz[tid + 512] = sz[tid + 512];
        float* fs = (float*)(myst + 8192) + tid * 6;
        fs[0] = cC[0]; fs[1] = cC[1]; fs[2] = ceS[0]; fs[3] = ceS[1];
        fs[4] = h2[0]; fs[5] = h2[1];
    }
}

extern "C" void kernel_launch(void* const* d_in, const int* in_sizes, int n_in,
                              void* d_out, int out_size, void* d_ws, size_t ws_size,
                              hipStream_t stream) {
    const float* x   = (const float*)d_in[0];
    const float* td  = (const float*)d_in[1];
    const float* Wi  = (const float*)d_in[2];
    const float* bi  = (const float*)d_in[3];
    const float* Wf  = (const float*)d_in[4];
    const float* bf  = (const float*)d_in[5];
    const float* Wie = (const float*)d_in[6];
    const float* bie = (const float*)d_in[7];
    const float* Wfe = (const float*)d_in[8];
    const float* bfe = (const float*)d_in[9];
    const float* Wz  = (const float*)d_in[10];
    const float* bz  = (const float*)d_in[11];
    const float* Wo  = (const float*)d_in[12];
    const float* bo  = (const float*)d_in[13];
    const float* Wd  = (const float*)d_in[14];
    const float* bd  = (const float*)d_in[15];
    const float* be  = (const float*)d_in[16];

    char* hbuf  = (char*)d_ws;                       // 128 KB records (memset)
    char* stbuf = (char*)d_ws + 131072;              // 512 KB chunk state
    unsigned short* ringbf = (unsigned short*)((char*)d_ws + 655360);

    const size_t perstep = (size_t)4 * 97 * 256 * 2; // 198656 B bf16 Gx per step
    int chunk = 1024;
    while (chunk > 16 && ws_size < 655360 + (size_t)chunk * perstep) chunk >>= 1;

    hipMemsetAsync(d_ws, 0, 131072, stream);         // replay safety: stale seqs
    for (int t0 = 0; t0 < LSEQ; t0 += chunk) {
        hipLaunchKernelGGL(gx_kernel, dim3(128), dim3(512), 0, stream,
                           x, Wi, bi, Wf, bf, Wie, bie, Wfe, bfe, Wz, bz, Wo, bo,
                           Wd, bd, ringbf, t0, chunk >> 3);
        hipLaunchKernelGGL(rec_kernel, dim3(16), dim3(512), 0, stream,
                           td, Wi, Wf, Wie, Wfe, Wz, Wo, Wd, be,
                           (float*)d_out, hbuf, ringbf, stbuf, t0, t0 + chunk);
    }
}